// Round 2
// baseline (853.775 us; speedup 1.0000x reference)
//
#include <hip/hip_runtime.h>

typedef _Float16 f16;
typedef _Float16 f16x4 __attribute__((ext_vector_type(4)));
typedef _Float16 f16x8 __attribute__((ext_vector_type(8)));
typedef float f32x4 __attribute__((ext_vector_type(4)));

__device__ __forceinline__ f32x4 mfma16(f16x8 a, f16x8 b, f32x4 c) {
  return __builtin_amdgcn_mfma_f32_16x16x32_f16(a, b, c, 0, 0, 0);
}

__device__ __forceinline__ float sigmoid_(float x) { return 1.f / (1.f + __expf(-x)); }
__device__ __forceinline__ float tanh_(float x) { return 1.f - 2.f / (__expf(2.f * x) + 1.f); }

// ---------------------------------------------------------------------------
// fp32 -> fp16 conversion, 4 elements/thread
// ---------------------------------------------------------------------------
__global__ void cvt_kernel(const float* __restrict__ src, f16* __restrict__ dst, int n4) {
  int i = blockIdx.x * 256 + threadIdx.x;
  if (i < n4) {
    float4 v = ((const float4*)src)[i];
    f16x4 h = {(f16)v.x, (f16)v.y, (f16)v.z, (f16)v.w};
    ((f16x4*)dst)[i] = h;
  }
}

// ---------------------------------------------------------------------------
// GEMM1: P[split][2048][512] (f16 partials) = v[2048,20000] @ W_down^T slabs.
// 128x128 tiles, ksplit 8, register-double-buffered staging (no atomics).
// grid (8 ksplit, 64 tiles); XCD = blockIdx.x % 8 pins each k-slab of B to one
// XCD's L2 (1.25 MB/slab).
// ---------------------------------------------------------------------------
__global__ __launch_bounds__(256, 2) void gemm1_kernel(
    const float* __restrict__ A, const f16* __restrict__ B, f16* __restrict__ P) {
  constexpr int K = 20000;
  __shared__ f16 Al[128][40];
  __shared__ f16 Bl[128][40];
  int tid = threadIdx.x;
  int split = blockIdx.x;
  int m0 = (blockIdx.y >> 2) * 128, n0 = (blockIdx.y & 3) * 128;
  int it0 = (split * 625) >> 3, it1 = ((split + 1) * 625) >> 3;
  int wid = tid >> 6, lane = tid & 63;
  int wm = wid & 1, wn = wid >> 1;
  int lm = lane & 15, quad = lane >> 4;
  int srow = tid >> 1, sseg = (tid & 1) * 16;

  const float* aptr = A + (size_t)(m0 + srow) * K + sseg;
  const f16* bptr = B + (size_t)(n0 + srow) * K + sseg;

  float4 Ar0, Ar1, Ar2, Ar3;
  f16x8 Br0, Br1;
  {
    int k0 = it0 * 32;
    Ar0 = *(const float4*)(aptr + k0);
    Ar1 = *(const float4*)(aptr + k0 + 4);
    Ar2 = *(const float4*)(aptr + k0 + 8);
    Ar3 = *(const float4*)(aptr + k0 + 12);
    Br0 = *(const f16x8*)(bptr + k0);
    Br1 = *(const f16x8*)(bptr + k0 + 8);
  }

  f32x4 acc[4][4];
#pragma unroll
  for (int i = 0; i < 4; ++i)
#pragma unroll
    for (int j = 0; j < 4; ++j) acc[i][j] = (f32x4){0.f, 0.f, 0.f, 0.f};

  for (int it = it0; it < it1; ++it) {
    __syncthreads();  // prev compute done, LDS writable
    f16x8 pa0 = {(f16)Ar0.x, (f16)Ar0.y, (f16)Ar0.z, (f16)Ar0.w,
                 (f16)Ar1.x, (f16)Ar1.y, (f16)Ar1.z, (f16)Ar1.w};
    f16x8 pa1 = {(f16)Ar2.x, (f16)Ar2.y, (f16)Ar2.z, (f16)Ar2.w,
                 (f16)Ar3.x, (f16)Ar3.y, (f16)Ar3.z, (f16)Ar3.w};
    *(f16x8*)&Al[srow][sseg] = pa0;
    *(f16x8*)&Al[srow][sseg + 8] = pa1;
    *(f16x8*)&Bl[srow][sseg] = Br0;
    *(f16x8*)&Bl[srow][sseg + 8] = Br1;
    if (it + 1 < it1) {  // prefetch next k-tile into regs; latency hidden by MFMA
      int kn = (it + 1) * 32;
      Ar0 = *(const float4*)(aptr + kn);
      Ar1 = *(const float4*)(aptr + kn + 4);
      Ar2 = *(const float4*)(aptr + kn + 8);
      Ar3 = *(const float4*)(aptr + kn + 12);
      Br0 = *(const f16x8*)(bptr + kn);
      Br1 = *(const f16x8*)(bptr + kn + 8);
    }
    __syncthreads();
    f16x8 af[4], bf[4];
#pragma unroll
    for (int mi = 0; mi < 4; ++mi) af[mi] = *(const f16x8*)&Al[wm * 64 + mi * 16 + lm][quad * 8];
#pragma unroll
    for (int ni = 0; ni < 4; ++ni) bf[ni] = *(const f16x8*)&Bl[wn * 64 + ni * 16 + lm][quad * 8];
#pragma unroll
    for (int mi = 0; mi < 4; ++mi)
#pragma unroll
      for (int ni = 0; ni < 4; ++ni) acc[mi][ni] = mfma16(af[mi], bf[ni], acc[mi][ni]);
  }
  size_t base = (size_t)split * 2048;
#pragma unroll
  for (int mi = 0; mi < 4; ++mi)
#pragma unroll
    for (int ni = 0; ni < 4; ++ni)
#pragma unroll
      for (int r = 0; r < 4; ++r) {
        int row = m0 + wm * 64 + mi * 16 + quad * 4 + r;
        int col = n0 + wn * 64 + ni * 16 + lm;
        P[(base + row) * 512 + col] = (f16)acc[mi][ni][r];
      }
}

// ---------------------------------------------------------------------------
// build vt[2048,640] f16 = [ sum_8 P | t*Wt_up_w + Wt_up_b ]
// ---------------------------------------------------------------------------
__global__ void build_vt_kernel(const f16* __restrict__ P, const float* __restrict__ t,
                                const float* __restrict__ wtw, const float* __restrict__ wtb,
                                f16* __restrict__ vt) {
  int m = blockIdx.x;
  float tv = t[m];
  for (int c = threadIdx.x; c < 640; c += 256) {
    float val;
    if (c < 512) {
      val = 0.f;
#pragma unroll
      for (int s = 0; s < 8; ++s) val += (float)P[((size_t)s * 2048 + m) * 512 + c];
    } else {
      val = tv * wtw[c - 512] + wtb[c - 512];
    }
    vt[(size_t)m * 640 + c] = (f16)val;
  }
}

// ---------------------------------------------------------------------------
// 128x128-tile fp16 GEMM: C[M,N] = A[M,K] @ Bt[N,K]^T  (both K-contiguous)
// EPI 0: plain f16 store. EPI 1: xg layout (l,b swap) + bias add.
// ---------------------------------------------------------------------------
template <int EPI>
__global__ __launch_bounds__(256, 2) void gemm128_kernel(
    const f16* __restrict__ A, const f16* __restrict__ B, f16* __restrict__ out,
    const float* __restrict__ bias0, const float* __restrict__ bias1, int K_iters, int N) {
  __shared__ f16 Al[128][40];
  __shared__ f16 Bl[128][40];
  int tid = threadIdx.x;
  int m0 = blockIdx.y * 128, n0 = blockIdx.x * 128;
  int wid = tid >> 6, lane = tid & 63;
  int wm = wid & 1, wn = wid >> 1;
  int lm = lane & 15, quad = lane >> 4;
  int K = K_iters * 32;

  f32x4 acc[4][4];
#pragma unroll
  for (int i = 0; i < 4; ++i)
#pragma unroll
    for (int j = 0; j < 4; ++j) acc[i][j] = (f32x4){0.f, 0.f, 0.f, 0.f};

  for (int it = 0; it < K_iters; ++it) {
    int k0 = it * 32;
    __syncthreads();
#pragma unroll
    for (int i = 0; i < 2; ++i) {
      int slot = tid + i * 256;
      int row = slot >> 2, seg = slot & 3;
      *(f16x8*)&Al[row][seg * 8] = *(const f16x8*)(A + (size_t)(m0 + row) * K + k0 + seg * 8);
      *(f16x8*)&Bl[row][seg * 8] = *(const f16x8*)(B + (size_t)(n0 + row) * K + k0 + seg * 8);
    }
    __syncthreads();
    f16x8 af[4], bf[4];
#pragma unroll
    for (int mi = 0; mi < 4; ++mi) af[mi] = *(const f16x8*)&Al[wm * 64 + mi * 16 + lm][quad * 8];
#pragma unroll
    for (int ni = 0; ni < 4; ++ni) bf[ni] = *(const f16x8*)&Bl[wn * 64 + ni * 16 + lm][quad * 8];
#pragma unroll
    for (int mi = 0; mi < 4; ++mi)
#pragma unroll
      for (int ni = 0; ni < 4; ++ni) acc[mi][ni] = mfma16(af[mi], bf[ni], acc[mi][ni]);
  }
#pragma unroll
  for (int mi = 0; mi < 4; ++mi)
#pragma unroll
    for (int ni = 0; ni < 4; ++ni)
#pragma unroll
      for (int r = 0; r < 4; ++r) {
        int row = m0 + wm * 64 + mi * 16 + quad * 4 + r;
        int col = n0 + wn * 64 + ni * 16 + lm;
        float val = acc[mi][ni][r];
        if (EPI == 0) {
          out[(size_t)row * N + col] = (f16)val;
        } else {
          int l = row & 15, b = row >> 4;
          out[(size_t)(l * 128 + b) * N + col] = (f16)(val + bias0[col] + bias1[col]);
        }
      }
}

// ---------------------------------------------------------------------------
// Persistent LSTM: all 16 steps in ONE kernel. 128 blocks (1/CU guaranteed
// resident: 149.5 KB LDS). Block = (hid-slice of 16) x (batch-half of 64).
// W_hh slice lives in LDS for the whole kernel; c-state in registers;
// h ping-pongs through global f16 with a device-scope grid barrier per step.
// ---------------------------------------------------------------------------
__global__ __launch_bounds__(256, 1) void lstm_persist_kernel(
    const f16* __restrict__ Whh, const f16* __restrict__ xg, f16* __restrict__ hb0,
    f16* __restrict__ hb1, float* __restrict__ hf32, unsigned int* __restrict__ bar) {
  __shared__ f16 Wl[64 * 1032];     // 4 gates x 16 hid rows, K=1024 (+8 pad: 2-way banks)
  __shared__ float gl[4][64][17];   // gate exchange [g][b][hid]
  int tid = threadIdx.x;
  int w = tid >> 6, lane = tid & 63;
  int lm = lane & 15, quad = lane >> 4;
  int hs = blockIdx.x >> 1, bs = blockIdx.x & 1;
  int h0 = hs * 16;

  // one-time W_hh slice load: row r -> gate r>>4, hid h0+(r&15)
  for (int i = tid; i < 8192; i += 256) {
    int r = i >> 7, kk = (i & 127) * 8;
    int g = r >> 4, hr = h0 + (r & 15);
    *(f16x8*)&Wl[r * 1032 + kk] = *(const f16x8*)(Whh + ((size_t)(g << 10) + hr) * 1024 + kk);
  }
  float creg[4] = {0.f, 0.f, 0.f, 0.f};
  int bl = tid >> 2, hb = (tid & 3) * 4;
  __syncthreads();

  const f16* hcur = hb0;
  f16* hnxt = hb1;
  for (int s = 0; s < 16; ++s) {
    // GEMM: gates[gate w][64 b][16 hid] over K=1024
    f32x4 acc[4];
#pragma unroll
    for (int mt = 0; mt < 4; ++mt) acc[mt] = (f32x4){0.f, 0.f, 0.f, 0.f};
    const f16* hrow = hcur + (size_t)(bs * 64 + lm) * 1024;
    const f16* wbase = &Wl[(w * 16 + lm) * 1032 + quad * 8];
    f16x8 an[4];
    {
      int kq = quad * 8;
      an[0] = *(const f16x8*)(hrow + kq);
      an[1] = *(const f16x8*)(hrow + 16384 + kq);
      an[2] = *(const f16x8*)(hrow + 32768 + kq);
      an[3] = *(const f16x8*)(hrow + 49152 + kq);
    }
    for (int it = 0; it < 32; ++it) {
      f16x8 b = *(const f16x8*)(wbase + it * 32);
      f16x8 a0 = an[0], a1 = an[1], a2 = an[2], a3 = an[3];
      if (it < 31) {  // prefetch next k-chunk of h (L1-hot: all 4 waves share)
        int kq = (it + 1) * 32 + quad * 8;
        an[0] = *(const f16x8*)(hrow + kq);
        an[1] = *(const f16x8*)(hrow + 16384 + kq);
        an[2] = *(const f16x8*)(hrow + 32768 + kq);
        an[3] = *(const f16x8*)(hrow + 49152 + kq);
      }
      acc[0] = mfma16(a0, b, acc[0]);
      acc[1] = mfma16(a1, b, acc[1]);
      acc[2] = mfma16(a2, b, acc[2]);
      acc[3] = mfma16(a3, b, acc[3]);
    }
#pragma unroll
    for (int mt = 0; mt < 4; ++mt)
#pragma unroll
      for (int r = 0; r < 4; ++r) gl[w][mt * 16 + quad * 4 + r][lm] = acc[mt][r];
    __syncthreads();
    // elementwise: 4 (b,hid) pairs per thread; c lives in creg across steps
    const f16* xr = xg + ((size_t)(s * 128 + bs * 64 + bl)) * 4096 + h0 + hb;
    f16x4 xi = *(const f16x4*)(xr);
    f16x4 xf = *(const f16x4*)(xr + 1024);
    f16x4 xgg = *(const f16x4*)(xr + 2048);
    f16x4 xo = *(const f16x4*)(xr + 3072);
    f16x4 hv;
    float hf[4];
#pragma unroll
    for (int j = 0; j < 4; ++j) {
      float gi = (float)xi[j] + gl[0][bl][hb + j];
      float gf = (float)xf[j] + gl[1][bl][hb + j];
      float gg = (float)xgg[j] + gl[2][bl][hb + j];
      float go = (float)xo[j] + gl[3][bl][hb + j];
      float iv = sigmoid_(gi), fv = sigmoid_(gf), gv = tanh_(gg), ov = sigmoid_(go);
      creg[j] = fv * creg[j] + iv * gv;
      float hh = ov * tanh_(creg[j]);
      hv[j] = (f16)hh;
      hf[j] = hh;
    }
    *(f16x4*)(hnxt + (size_t)(bs * 64 + bl) * 1024 + h0 + hb) = hv;
    if (s == 15) {
      *(float4*)(hf32 + (size_t)(bs * 64 + bl) * 1024 + h0 + hb) =
          make_float4(hf[0], hf[1], hf[2], hf[3]);
    } else {
      // device-scope grid barrier (monotone counter, memset to 0 per launch)
      __syncthreads();  // drains each wave's vmcnt -> h stores are in L2
      if (tid == 0) {
        __threadfence();  // release: write back L2 (cross-XCD visibility)
        __hip_atomic_fetch_add(bar, 1u, __ATOMIC_RELEASE, __HIP_MEMORY_SCOPE_AGENT);
        unsigned target = (unsigned)(s + 1) * 128u;
        while (__hip_atomic_load(bar, __ATOMIC_ACQUIRE, __HIP_MEMORY_SCOPE_AGENT) < target)
          __builtin_amdgcn_s_sleep(4);
        __threadfence();  // acquire: invalidate L1/L2
      }
      __syncthreads();
    }
    const f16* tmp = hcur;
    hcur = hnxt;
    hnxt = (f16*)tmp;
  }
}

// ---------------------------------------------------------------------------
// pred[b] = dot(h[b], lin_w) + lin_b
// ---------------------------------------------------------------------------
__global__ void pred_kernel(const float* __restrict__ h, const float* __restrict__ w,
                            const float* __restrict__ b, float* __restrict__ out) {
  int bb = blockIdx.x, tid = threadIdx.x;
  float4 hv = *(const float4*)(h + (size_t)bb * 1024 + tid * 4);
  float4 wv = *(const float4*)(w + tid * 4);
  float s = hv.x * wv.x + hv.y * wv.y + hv.z * wv.z + hv.w * wv.w;
#pragma unroll
  for (int off = 32; off > 0; off >>= 1) s += __shfl_down(s, off);
  __shared__ float red[4];
  if ((tid & 63) == 0) red[tid >> 6] = s;
  __syncthreads();
  if (tid == 0) out[bb] = red[0] + red[1] + red[2] + red[3] + b[0];
}

// ---------------------------------------------------------------------------
extern "C" void kernel_launch(void* const* d_in, const int* in_sizes, int n_in,
                              void* d_out, int out_size, void* d_ws, size_t ws_size,
                              hipStream_t stream) {
  (void)in_sizes; (void)n_in; (void)out_size; (void)ws_size;
  const float* v      = (const float*)d_in[0];
  const float* t      = (const float*)d_in[1];
  const float* W_down = (const float*)d_in[2];
  const float* Wt_w   = (const float*)d_in[3];
  const float* Wt_b   = (const float*)d_in[4];
  const float* W_vt   = (const float*)d_in[5];
  const float* W_ih   = (const float*)d_in[6];
  const float* W_hh   = (const float*)d_in[7];
  const float* b_ih   = (const float*)d_in[8];
  const float* b_hh   = (const float*)d_in[9];
  const float* lin_w  = (const float*)d_in[10];
  const float* lin_b  = (const float*)d_in[11];

  char* ws = (char*)d_ws;
  constexpr size_t OFF_WDOWN = 0;         // 20,480,000 : W_down f16 [512][20000]
  constexpr size_t OFF_WVT   = 20480000;  //    655,360 : W_vt  f16 [512][640]
  constexpr size_t OFF_WIH   = 21135360;  //  4,194,304 : W_ih  f16 [4096][512]
  constexpr size_t OFF_WHH   = 25329664;  //  8,388,608 : W_hh  f16 [4096][1024]
  constexpr size_t OFF_VT    = 33718272;  //  2,621,440 : vt    f16 [2048][640]
  constexpr size_t OFF_IN    = 36339712;  //  2,097,152 : inputs f16 [2048][512]
  constexpr size_t OFF_XG    = 38436864;  // 16,777,216 : P f16 [8][2048][512] then xg f16 [16][128][4096]
  constexpr size_t OFF_H0    = 55214080;  //    262,144 : h ping f16
  constexpr size_t OFF_BAR   = 55476224;  //        256 : grid-barrier counter
  constexpr size_t OFF_H1    = 55476480;  //    262,144 : h pong f16
  constexpr size_t OFF_HF    = 55738624;  //    524,288 : h f32 (final)
  // total 56,262,912 B (< 61 MB proven available in R0)

  f16* wdown16 = (f16*)(ws + OFF_WDOWN);
  f16* wvt16   = (f16*)(ws + OFF_WVT);
  f16* wih16   = (f16*)(ws + OFF_WIH);
  f16* whh16   = (f16*)(ws + OFF_WHH);
  f16* vt16    = (f16*)(ws + OFF_VT);
  f16* in16    = (f16*)(ws + OFF_IN);
  f16* pxg     = (f16*)(ws + OFF_XG);
  float* hf32  = (float*)(ws + OFF_HF);
  unsigned* bar = (unsigned*)(ws + OFF_BAR);

  hipMemsetAsync(ws + OFF_H0, 0, 262400, stream);  // h0 + bar

  cvt_kernel<<<10000, 256, 0, stream>>>(W_down, wdown16, 2560000);
  cvt_kernel<<<320, 256, 0, stream>>>(W_vt, wvt16, 81920);
  cvt_kernel<<<2048, 256, 0, stream>>>(W_ih, wih16, 524288);
  cvt_kernel<<<4096, 256, 0, stream>>>(W_hh, whh16, 1048576);

  gemm1_kernel<<<dim3(8, 64), 256, 0, stream>>>(v, wdown16, pxg);
  build_vt_kernel<<<2048, 256, 0, stream>>>(pxg, t, Wt_w, Wt_b, vt16);
  gemm128_kernel<0><<<dim3(4, 16), 256, 0, stream>>>(vt16, wvt16, in16, nullptr, nullptr, 20, 512);
  gemm128_kernel<1><<<dim3(32, 16), 256, 0, stream>>>(in16, wih16, pxg, b_ih, b_hh, 16, 4096);

  lstm_persist_kernel<<<128, 256, 0, stream>>>(whh16, pxg, (f16*)(ws + OFF_H0),
                                               (f16*)(ws + OFF_H1), hf32, bar);
  pred_kernel<<<128, 256, 0, stream>>>(hf32, lin_w, lin_b, (float*)d_out);
}

// Round 3
// 544.524 us; speedup vs baseline: 1.5679x; 1.5679x over previous
//
#include <hip/hip_runtime.h>

typedef _Float16 f16;
typedef _Float16 f16x2 __attribute__((ext_vector_type(2)));
typedef _Float16 f16x4 __attribute__((ext_vector_type(4)));
typedef _Float16 f16x8 __attribute__((ext_vector_type(8)));
typedef float f32x4 __attribute__((ext_vector_type(4)));

__device__ __forceinline__ f32x4 mfma16(f16x8 a, f16x8 b, f32x4 c) {
  return __builtin_amdgcn_mfma_f32_16x16x32_f16(a, b, c, 0, 0, 0);
}

__device__ __forceinline__ float sigmoid_(float x) { return 1.f / (1.f + __expf(-x)); }
__device__ __forceinline__ float tanh_(float x) { return 1.f - 2.f / (__expf(2.f * x) + 1.f); }

// ---------------------------------------------------------------------------
// fp32 -> fp16 conversion, 4 elements/thread
// ---------------------------------------------------------------------------
__global__ void cvt_kernel(const float* __restrict__ src, f16* __restrict__ dst, int n4) {
  int i = blockIdx.x * 256 + threadIdx.x;
  if (i < n4) {
    float4 v = ((const float4*)src)[i];
    f16x4 h = {(f16)v.x, (f16)v.y, (f16)v.z, (f16)v.w};
    ((f16x4*)dst)[i] = h;
  }
}

// ---------------------------------------------------------------------------
// GEMM1: P[split][2048][512] (f16 partials) = v[2048,20000] @ W_down^T slabs.
// 128x128 tiles, ksplit 8, register-double-buffered staging (no atomics).
// ---------------------------------------------------------------------------
__global__ __launch_bounds__(256, 2) void gemm1_kernel(
    const float* __restrict__ A, const f16* __restrict__ B, f16* __restrict__ P) {
  constexpr int K = 20000;
  __shared__ f16 Al[128][40];
  __shared__ f16 Bl[128][40];
  int tid = threadIdx.x;
  int split = blockIdx.x;
  int m0 = (blockIdx.y >> 2) * 128, n0 = (blockIdx.y & 3) * 128;
  int it0 = (split * 625) >> 3, it1 = ((split + 1) * 625) >> 3;
  int wid = tid >> 6, lane = tid & 63;
  int wm = wid & 1, wn = wid >> 1;
  int lm = lane & 15, quad = lane >> 4;
  int srow = tid >> 1, sseg = (tid & 1) * 16;

  const float* aptr = A + (size_t)(m0 + srow) * K + sseg;
  const f16* bptr = B + (size_t)(n0 + srow) * K + sseg;

  float4 Ar0, Ar1, Ar2, Ar3;
  f16x8 Br0, Br1;
  {
    int k0 = it0 * 32;
    Ar0 = *(const float4*)(aptr + k0);
    Ar1 = *(const float4*)(aptr + k0 + 4);
    Ar2 = *(const float4*)(aptr + k0 + 8);
    Ar3 = *(const float4*)(aptr + k0 + 12);
    Br0 = *(const f16x8*)(bptr + k0);
    Br1 = *(const f16x8*)(bptr + k0 + 8);
  }

  f32x4 acc[4][4];
#pragma unroll
  for (int i = 0; i < 4; ++i)
#pragma unroll
    for (int j = 0; j < 4; ++j) acc[i][j] = (f32x4){0.f, 0.f, 0.f, 0.f};

  for (int it = it0; it < it1; ++it) {
    __syncthreads();
    f16x8 pa0 = {(f16)Ar0.x, (f16)Ar0.y, (f16)Ar0.z, (f16)Ar0.w,
                 (f16)Ar1.x, (f16)Ar1.y, (f16)Ar1.z, (f16)Ar1.w};
    f16x8 pa1 = {(f16)Ar2.x, (f16)Ar2.y, (f16)Ar2.z, (f16)Ar2.w,
                 (f16)Ar3.x, (f16)Ar3.y, (f16)Ar3.z, (f16)Ar3.w};
    *(f16x8*)&Al[srow][sseg] = pa0;
    *(f16x8*)&Al[srow][sseg + 8] = pa1;
    *(f16x8*)&Bl[srow][sseg] = Br0;
    *(f16x8*)&Bl[srow][sseg + 8] = Br1;
    if (it + 1 < it1) {
      int kn = (it + 1) * 32;
      Ar0 = *(const float4*)(aptr + kn);
      Ar1 = *(const float4*)(aptr + kn + 4);
      Ar2 = *(const float4*)(aptr + kn + 8);
      Ar3 = *(const float4*)(aptr + kn + 12);
      Br0 = *(const f16x8*)(bptr + kn);
      Br1 = *(const f16x8*)(bptr + kn + 8);
    }
    __syncthreads();
    f16x8 af[4], bf[4];
#pragma unroll
    for (int mi = 0; mi < 4; ++mi) af[mi] = *(const f16x8*)&Al[wm * 64 + mi * 16 + lm][quad * 8];
#pragma unroll
    for (int ni = 0; ni < 4; ++ni) bf[ni] = *(const f16x8*)&Bl[wn * 64 + ni * 16 + lm][quad * 8];
#pragma unroll
    for (int mi = 0; mi < 4; ++mi)
#pragma unroll
      for (int ni = 0; ni < 4; ++ni) acc[mi][ni] = mfma16(af[mi], bf[ni], acc[mi][ni]);
  }
  size_t base = (size_t)split * 2048;
#pragma unroll
  for (int mi = 0; mi < 4; ++mi)
#pragma unroll
    for (int ni = 0; ni < 4; ++ni)
#pragma unroll
      for (int r = 0; r < 4; ++r) {
        int row = m0 + wm * 64 + mi * 16 + quad * 4 + r;
        int col = n0 + wn * 64 + ni * 16 + lm;
        P[(base + row) * 512 + col] = (f16)acc[mi][ni][r];
      }
}

// ---------------------------------------------------------------------------
// build vt[2048,640] f16 = [ sum_8 P | t*Wt_up_w + Wt_up_b ]
// ---------------------------------------------------------------------------
__global__ void build_vt_kernel(const f16* __restrict__ P, const float* __restrict__ t,
                                const float* __restrict__ wtw, const float* __restrict__ wtb,
                                f16* __restrict__ vt) {
  int m = blockIdx.x;
  float tv = t[m];
  for (int c = threadIdx.x; c < 640; c += 256) {
    float val;
    if (c < 512) {
      val = 0.f;
#pragma unroll
      for (int s = 0; s < 8; ++s) val += (float)P[((size_t)s * 2048 + m) * 512 + c];
    } else {
      val = tv * wtw[c - 512] + wtb[c - 512];
    }
    vt[(size_t)m * 640 + c] = (f16)val;
  }
}

// ---------------------------------------------------------------------------
// 128x128-tile fp16 GEMM: C[M,N] = A[M,K] @ Bt[N,K]^T  (both K-contiguous)
// EPI 0: plain f16 store. EPI 1: xg layout (l,b swap) + bias add.
// ---------------------------------------------------------------------------
template <int EPI>
__global__ __launch_bounds__(256, 2) void gemm128_kernel(
    const f16* __restrict__ A, const f16* __restrict__ B, f16* __restrict__ out,
    const float* __restrict__ bias0, const float* __restrict__ bias1, int K_iters, int N) {
  __shared__ f16 Al[128][40];
  __shared__ f16 Bl[128][40];
  int tid = threadIdx.x;
  int m0 = blockIdx.y * 128, n0 = blockIdx.x * 128;
  int wid = tid >> 6, lane = tid & 63;
  int wm = wid & 1, wn = wid >> 1;
  int lm = lane & 15, quad = lane >> 4;
  int K = K_iters * 32;

  f32x4 acc[4][4];
#pragma unroll
  for (int i = 0; i < 4; ++i)
#pragma unroll
    for (int j = 0; j < 4; ++j) acc[i][j] = (f32x4){0.f, 0.f, 0.f, 0.f};

  for (int it = 0; it < K_iters; ++it) {
    int k0 = it * 32;
    __syncthreads();
#pragma unroll
    for (int i = 0; i < 2; ++i) {
      int slot = tid + i * 256;
      int row = slot >> 2, seg = slot & 3;
      *(f16x8*)&Al[row][seg * 8] = *(const f16x8*)(A + (size_t)(m0 + row) * K + k0 + seg * 8);
      *(f16x8*)&Bl[row][seg * 8] = *(const f16x8*)(B + (size_t)(n0 + row) * K + k0 + seg * 8);
    }
    __syncthreads();
    f16x8 af[4], bf[4];
#pragma unroll
    for (int mi = 0; mi < 4; ++mi) af[mi] = *(const f16x8*)&Al[wm * 64 + mi * 16 + lm][quad * 8];
#pragma unroll
    for (int ni = 0; ni < 4; ++ni) bf[ni] = *(const f16x8*)&Bl[wn * 64 + ni * 16 + lm][quad * 8];
#pragma unroll
    for (int mi = 0; mi < 4; ++mi)
#pragma unroll
      for (int ni = 0; ni < 4; ++ni) acc[mi][ni] = mfma16(af[mi], bf[ni], acc[mi][ni]);
  }
#pragma unroll
  for (int mi = 0; mi < 4; ++mi)
#pragma unroll
    for (int ni = 0; ni < 4; ++ni)
#pragma unroll
      for (int r = 0; r < 4; ++r) {
        int row = m0 + wm * 64 + mi * 16 + quad * 4 + r;
        int col = n0 + wn * 64 + ni * 16 + lm;
        float val = acc[mi][ni][r];
        if (EPI == 0) {
          out[(size_t)row * N + col] = (f16)val;
        } else {
          int l = row & 15, b = row >> 4;
          out[(size_t)(l * 128 + b) * N + col] = (f16)(val + bias0[col] + bias1[col]);
        }
      }
}

// ---------------------------------------------------------------------------
// LSTM step v2 (one launch per step; kernel boundary = the barrier).
// Grid (64 hid-slices, 4 batch-slices) = 256 blocks. Block = 256 thr, wave = gate.
// h-slice [32][1024] staged once into LDS; W_hh B-frags from L2 with 8-deep
// register ring prefetch; c transposed [hid][batch] f32; h out via LDS bounce.
// ---------------------------------------------------------------------------
__global__ __launch_bounds__(256, 1) void lstm_step2_kernel(
    const f16* __restrict__ h_in, const f16* __restrict__ Whh,
    const f16* __restrict__ xg_l, float* __restrict__ cT, f16* __restrict__ h_out) {
  __shared__ f16 Alf[32 * 1032];   // h slice, +8 f16 pad per row (2-way banks = free)
  __shared__ float gl[4][32][17];  // gate exchange
  __shared__ f16 hx[32][18];       // h-out bounce
  int tid = threadIdx.x;
  int w = tid >> 6, lane = tid & 63;
  int lm = lane & 15, quad = lane >> 4;
  int h0 = blockIdx.x * 16;  // hid base
  int b0 = blockIdx.y * 32;  // batch base

  // stage h[b0..b0+32][0..1024] -> LDS (16 coalesced 16B rounds)
#pragma unroll
  for (int i = 0; i < 16; ++i) {
    int idx = i * 256 + tid;
    int r = idx >> 7, c8 = (idx & 127) * 8;
    *(f16x8*)&Alf[r * 1032 + c8] = *(const f16x8*)(h_in + (size_t)(b0 + r) * 1024 + c8);
  }
  // wave w = gate w; its 16 W rows = [w*1024 + h0 .. +16]
  const f16* wrow = Whh + ((size_t)(w << 10) + h0 + lm) * 1024 + quad * 8;
  f16x8 Bv[8];
#pragma unroll
  for (int j = 0; j < 8; ++j) Bv[j] = *(const f16x8*)(wrow + j * 32);
  f32x4 acc0 = {0.f, 0.f, 0.f, 0.f}, acc1 = {0.f, 0.f, 0.f, 0.f};
  __syncthreads();
#pragma unroll
  for (int it = 0; it < 32; ++it) {
    f16x8 bfr = Bv[it & 7];
    if (it < 24) Bv[it & 7] = *(const f16x8*)(wrow + (it + 8) * 32);
    f16x8 a0 = *(const f16x8*)&Alf[lm * 1032 + it * 32 + quad * 8];
    f16x8 a1 = *(const f16x8*)&Alf[(16 + lm) * 1032 + it * 32 + quad * 8];
    acc0 = mfma16(a0, bfr, acc0);
    acc1 = mfma16(a1, bfr, acc1);
  }
#pragma unroll
  for (int r = 0; r < 4; ++r) {
    gl[w][quad * 4 + r][lm] = acc0[r];
    gl[w][16 + quad * 4 + r][lm] = acc1[r];
  }
  __syncthreads();
  // elementwise: (b 0..31) x (hl 0..15); lanes vary b fast (coalesced cT)
#pragma unroll
  for (int half = 0; half < 2; ++half) {
    int b = tid & 31, hl = (tid >> 5) + half * 8;
    int gb = b0 + b, gh = h0 + hl;
    const f16* xr = xg_l + (size_t)gb * 4096 + gh;
    float gi = (float)xr[0] + gl[0][b][hl];
    float gf = (float)xr[1024] + gl[1][b][hl];
    float gg = (float)xr[2048] + gl[2][b][hl];
    float go = (float)xr[3072] + gl[3][b][hl];
    float iv = sigmoid_(gi), fv = sigmoid_(gf), gv = tanh_(gg), ov = sigmoid_(go);
    size_t ci = (size_t)gh * 128 + gb;
    float cc = fv * cT[ci] + iv * gv;
    cT[ci] = cc;
    hx[b][hl] = (f16)(ov * tanh_(cc));
  }
  __syncthreads();
  {  // h_out write: 32 rows x 16 f16, 8 lanes/row of f16x2 (32B runs)
    int b = tid >> 3, e = (tid & 7) * 2;
    f16x2 hv = {hx[b][e], hx[b][e + 1]};
    *(f16x2*)(h_out + (size_t)(b0 + b) * 1024 + h0 + e) = hv;
  }
}

// ---------------------------------------------------------------------------
// pred[b] = dot(h[b] (f16), lin_w) + lin_b
// ---------------------------------------------------------------------------
__global__ void pred_kernel(const f16* __restrict__ h, const float* __restrict__ w,
                            const float* __restrict__ b, float* __restrict__ out) {
  int bb = blockIdx.x, tid = threadIdx.x;
  f16x4 hv = *(const f16x4*)(h + (size_t)bb * 1024 + tid * 4);
  float4 wv = *(const float4*)(w + tid * 4);
  float s = (float)hv[0] * wv.x + (float)hv[1] * wv.y + (float)hv[2] * wv.z + (float)hv[3] * wv.w;
#pragma unroll
  for (int off = 32; off > 0; off >>= 1) s += __shfl_down(s, off);
  __shared__ float red[4];
  if ((tid & 63) == 0) red[tid >> 6] = s;
  __syncthreads();
  if (tid == 0) out[bb] = red[0] + red[1] + red[2] + red[3] + b[0];
}

// ---------------------------------------------------------------------------
extern "C" void kernel_launch(void* const* d_in, const int* in_sizes, int n_in,
                              void* d_out, int out_size, void* d_ws, size_t ws_size,
                              hipStream_t stream) {
  (void)in_sizes; (void)n_in; (void)out_size; (void)ws_size;
  const float* v      = (const float*)d_in[0];
  const float* t      = (const float*)d_in[1];
  const float* W_down = (const float*)d_in[2];
  const float* Wt_w   = (const float*)d_in[3];
  const float* Wt_b   = (const float*)d_in[4];
  const float* W_vt   = (const float*)d_in[5];
  const float* W_ih   = (const float*)d_in[6];
  const float* W_hh   = (const float*)d_in[7];
  const float* b_ih   = (const float*)d_in[8];
  const float* b_hh   = (const float*)d_in[9];
  const float* lin_w  = (const float*)d_in[10];
  const float* lin_b  = (const float*)d_in[11];

  char* ws = (char*)d_ws;
  constexpr size_t OFF_WDOWN = 0;         // 20,480,000 : W_down f16 [512][20000]
  constexpr size_t OFF_WVT   = 20480000;  //    655,360 : W_vt  f16 [512][640]
  constexpr size_t OFF_WIH   = 21135360;  //  4,194,304 : W_ih  f16 [4096][512]
  constexpr size_t OFF_WHH   = 25329664;  //  8,388,608 : W_hh  f16 [4096][1024]
  constexpr size_t OFF_VT    = 33718272;  //  2,621,440 : vt    f16 [2048][640]
  constexpr size_t OFF_IN    = 36339712;  //  2,097,152 : inputs f16 [2048][512]
  constexpr size_t OFF_XG    = 38436864;  // 16,777,216 : P f16 [8][2048][512] then xg f16 [16][128][4096]
  constexpr size_t OFF_H0    = 55214080;  //    262,144 : h ping f16
  constexpr size_t OFF_C     = 55476224;  //    524,288 : c_T f32 [1024][128] (adjacent to H0 for one memset)
  constexpr size_t OFF_H1    = 56000512;  //    262,144 : h pong f16 (no init needed; fully written at s=0)

  f16* wdown16 = (f16*)(ws + OFF_WDOWN);
  f16* wvt16   = (f16*)(ws + OFF_WVT);
  f16* wih16   = (f16*)(ws + OFF_WIH);
  f16* whh16   = (f16*)(ws + OFF_WHH);
  f16* vt16    = (f16*)(ws + OFF_VT);
  f16* in16    = (f16*)(ws + OFF_IN);
  f16* pxg     = (f16*)(ws + OFF_XG);
  float* cT    = (float*)(ws + OFF_C);
  f16* hb[2]   = {(f16*)(ws + OFF_H0), (f16*)(ws + OFF_H1)};

  hipMemsetAsync(ws + OFF_H0, 0, 786432, stream);  // h0 + c_T

  cvt_kernel<<<10000, 256, 0, stream>>>(W_down, wdown16, 2560000);
  cvt_kernel<<<320, 256, 0, stream>>>(W_vt, wvt16, 81920);
  cvt_kernel<<<2048, 256, 0, stream>>>(W_ih, wih16, 524288);
  cvt_kernel<<<4096, 256, 0, stream>>>(W_hh, whh16, 1048576);

  gemm1_kernel<<<dim3(8, 64), 256, 0, stream>>>(v, wdown16, pxg);
  build_vt_kernel<<<2048, 256, 0, stream>>>(pxg, t, Wt_w, Wt_b, vt16);
  gemm128_kernel<0><<<dim3(4, 16), 256, 0, stream>>>(vt16, wvt16, in16, nullptr, nullptr, 20, 512);
  gemm128_kernel<1><<<dim3(32, 16), 256, 0, stream>>>(in16, wih16, pxg, b_ih, b_hh, 16, 4096);

  for (int s = 0; s < 16; ++s) {
    lstm_step2_kernel<<<dim3(64, 4), 256, 0, stream>>>(
        hb[s & 1], whh16, pxg + (size_t)s * 128 * 4096, cT, hb[(s + 1) & 1]);
  }
  pred_kernel<<<128, 256, 0, stream>>>(hb[0], lin_w, lin_b, (float*)d_out);
}